// Round 2
// baseline (484.788 us; speedup 1.0000x reference)
//
#include <hip/hip_runtime.h>
#include <hip/hip_bf16.h>

// Problem constants
// x: (4, 256, 64, 64) fp32
// w_down: (128, 256) ; b_down: (128)
// w_enc: (100, 128, 3, 3) ; b_enc: (100)
// w_out: (256, 256) ; b_out: (256)
// out z: (4, 256, 128, 128) fp32

#define NB    4
#define CIN   256
#define CD    128
#define CE    100
#define HW    64
#define NPIX  4096   // 64*64

// ---------------------------------------------------------------------------
// Kernel 1: 1x1 conv as GEMM.  C[n][m][pix] = sum_k A[m][k] * X[n][k][pix] (+bias)
// Tile: BM=64, BN=64, BK=16. 256 threads, 4x4 per thread.
// ---------------------------------------------------------------------------
__global__ __launch_bounds__(256) void gemm1x1_kernel(
    const float* __restrict__ A,    // M x K
    const float* __restrict__ X,    // NB x K x NPIX
    const float* __restrict__ bias, // M (or nullptr)
    float* __restrict__ C,          // NB x M x NPIX
    int M, int K)
{
    __shared__ __attribute__((aligned(16))) float As[16][68];
    __shared__ __attribute__((aligned(16))) float Bs[16][68];

    const int n  = blockIdx.z;
    const int m0 = blockIdx.y * 64;
    const int p0 = blockIdx.x * 64;
    const float* Xn = X + (size_t)n * K * NPIX;

    const int tid = threadIdx.x;
    const int tm = tid >> 4;   // 0..15
    const int tn = tid & 15;   // 0..15

    float acc[4][4] = {};

    for (int kt = 0; kt < K; kt += 16) {
        // A tile: As[k][m] = A[(m0+m)*K + kt+k]
        {
            int m  = tid >> 2;
            int k4 = (tid & 3) * 4;
            float4 av = *(const float4*)&A[(size_t)(m0 + m) * K + kt + k4];
            As[k4 + 0][m] = av.x;
            As[k4 + 1][m] = av.y;
            As[k4 + 2][m] = av.z;
            As[k4 + 3][m] = av.w;
        }
        // B tile: Bs[k][p] = Xn[(kt+k)*NPIX + p0+p]
        {
            int k = tid >> 6;   // 0..3
            int p = tid & 63;
            #pragma unroll
            for (int kk = 0; kk < 4; kk++)
                Bs[k + kk * 4][p] = Xn[(size_t)(kt + k + kk * 4) * NPIX + p0 + p];
        }
        __syncthreads();

        #pragma unroll
        for (int k = 0; k < 16; k++) {
            float4 a4 = *(const float4*)&As[k][tm * 4];
            float4 b4 = *(const float4*)&Bs[k][tn * 4];
            float av[4] = {a4.x, a4.y, a4.z, a4.w};
            float bv[4] = {b4.x, b4.y, b4.z, b4.w};
            #pragma unroll
            for (int i = 0; i < 4; i++)
                #pragma unroll
                for (int j = 0; j < 4; j++)
                    acc[i][j] += av[i] * bv[j];
        }
        __syncthreads();
    }

    #pragma unroll
    for (int i = 0; i < 4; i++) {
        int m = m0 + tm * 4 + i;
        float bb = bias ? bias[m] : 0.0f;
        float4 v;
        v.x = acc[i][0] + bb;
        v.y = acc[i][1] + bb;
        v.z = acc[i][2] + bb;
        v.w = acc[i][3] + bb;
        *(float4*)&C[((size_t)n * M + m) * NPIX + p0 + tn * 4] = v;
    }
}

// ---------------------------------------------------------------------------
// Kernel 2: 3x3 conv, pad=1.  t1 (4,128,64,64) -> e (4,100,64,64)
// Block: one 16x16 spatial tile, 25 output channels. Loop over 128 in-channels.
// ---------------------------------------------------------------------------
__global__ __launch_bounds__(256) void conv3x3_kernel(
    const float* __restrict__ T1,   // NB x CD x 64 x 64
    const float* __restrict__ W,    // CE x CD x 3 x 3
    const float* __restrict__ B,    // CE
    float* __restrict__ E)          // NB x CE x 64 x 64
{
    __shared__ float ts[18 * 18];
    __shared__ __attribute__((aligned(16))) float wsm[25][12];

    const int n    = blockIdx.z;
    const int cg   = blockIdx.y;          // 0..3 -> co = cg*25 + j
    const int tile = blockIdx.x;          // 0..15, 4x4 grid of 16x16 tiles
    const int th0  = (tile >> 2) * 16;
    const int tw0  = (tile & 3) * 16;

    const int tid = threadIdx.x;
    const int ph = tid >> 4;
    const int pw = tid & 15;

    const float* T1n = T1 + (size_t)n * CD * NPIX;

    float acc[25] = {};

    for (int c = 0; c < CD; c++) {
        __syncthreads();  // protect LDS from previous iteration's readers
        // stage 18x18 halo tile of channel c
        for (int e = tid; e < 324; e += 256) {
            int r  = e / 18;
            int cc = e - r * 18;
            int gh = th0 + r - 1;
            int gw = tw0 + cc - 1;
            float v = 0.0f;
            if ((unsigned)gh < 64u && (unsigned)gw < 64u)
                v = T1n[(size_t)c * NPIX + gh * 64 + gw];
            ts[e] = v;
        }
        // stage weights: 25 co x 9 taps (padded stride 12 for aligned float4)
        if (tid < 225) {
            int j = tid / 9;
            int t = tid - j * 9;
            wsm[j][t] = W[((size_t)(cg * 25 + j) * CD + c) * 9 + t];
        }
        __syncthreads();

        float px[9];
        #pragma unroll
        for (int dy = 0; dy < 3; dy++)
            #pragma unroll
            for (int dx = 0; dx < 3; dx++)
                px[dy * 3 + dx] = ts[(ph + dy) * 18 + pw + dx];

        #pragma unroll
        for (int j = 0; j < 25; j++) {
            float4 w0 = *(const float4*)&wsm[j][0];
            float4 w1 = *(const float4*)&wsm[j][4];
            float  w8 = wsm[j][8];
            acc[j] += w0.x * px[0] + w0.y * px[1] + w0.z * px[2]
                    + w0.w * px[3] + w1.x * px[4] + w1.y * px[5]
                    + w1.z * px[6] + w1.w * px[7] + w8 * px[8];
        }
    }

    #pragma unroll
    for (int j = 0; j < 25; j++) {
        int co = cg * 25 + j;
        E[((size_t)n * CE + co) * NPIX + (th0 + ph) * 64 + tw0 + pw] = acc[j] + B[co];
    }
}

// ---------------------------------------------------------------------------
// Kernel 3: softmax(25, per sub-pixel p) + CARAFE reassembly + bias,
// fused with pixel-shuffle. Uses xo = w_out @ x (computed at 64x64).
// z[n,o,2h+a,2w+b] = b_out[o] + sum_k sm[n,h,w,k,p] * xo_pad[n,o,h+di-2,w+dj-2]
//   with k = di*5+dj, p = a*2+b, sm = softmax_k(e[n, k*4+p, h, w]).
// Block: 8x8 spatial tile of one batch. 256 threads.
// ---------------------------------------------------------------------------
__global__ __launch_bounds__(256) void carafe_kernel(
    const float* __restrict__ E,    // NB x CE x 64 x 64
    const float* __restrict__ XO,   // NB x CIN x 64 x 64
    const float* __restrict__ Bout, // CIN
    float* __restrict__ Z)          // NB x CIN x 128 x 128
{
    __shared__ __attribute__((aligned(16))) float sm[25][64][4];  // 25.6 KB
    __shared__ float xs[64 * 12 * 12];                            // 36.9 KB

    const int n    = blockIdx.y;
    const int tile = blockIdx.x;          // 0..63, 8x8 grid of 8x8 tiles
    const int th0  = (tile >> 3) * 8;
    const int tw0  = (tile & 7) * 8;
    const int tid  = threadIdx.x;

    // ---- Phase 1: softmax over 25 kernel taps, for each (pixel, p) ----
    {
        int p   = tid & 3;
        int pix = tid >> 2;   // 0..63
        int gh  = th0 + (pix >> 3);
        int gw  = tw0 + (pix & 7);
        const float* En = E + (size_t)n * CE * NPIX + gh * 64 + gw;

        float v[25];
        float mx = -1e30f;
        #pragma unroll
        for (int k = 0; k < 25; k++) {
            v[k] = En[(size_t)(k * 4 + p) * NPIX];
            mx = fmaxf(mx, v[k]);
        }
        float s = 0.0f;
        #pragma unroll
        for (int k = 0; k < 25; k++) {
            v[k] = __expf(v[k] - mx);
            s += v[k];
        }
        float inv = 1.0f / s;
        #pragma unroll
        for (int k = 0; k < 25; k++)
            sm[k][pix][p] = v[k] * inv;
    }

    // ---- Phase 2: reassembly over 4 chunks of 64 output channels ----
    const int pix = tid & 63;
    const int og  = tid >> 6;   // 0..3
    const int ph  = pix >> 3;
    const int pw  = pix & 7;

    for (int oc = 0; oc < 4; oc++) {
        __syncthreads();
        // stage 64-channel 12x12 halo tile of xo
        for (int idx = tid; idx < 64 * 144; idx += 256) {
            int ch  = idx / 144;
            int rem = idx - ch * 144;
            int r   = rem / 12;
            int cc  = rem - r * 12;
            int gh  = th0 + r - 2;
            int gw  = tw0 + cc - 2;
            float val = 0.0f;
            if ((unsigned)gh < 64u && (unsigned)gw < 64u)
                val = XO[((size_t)n * CIN + oc * 64 + ch) * NPIX + gh * 64 + gw];
            xs[idx] = val;
        }
        __syncthreads();

        float acc[16][4] = {};
        for (int k = 0; k < 25; k++) {
            int di = k / 5;
            int dj = k - di * 5;
            float4 wv = *(const float4*)&sm[k][pix][0];
            int base = (ph + di) * 12 + pw + dj;
            #pragma unroll
            for (int i = 0; i < 16; i++) {
                float xv = xs[(og * 16 + i) * 144 + base];
                acc[i][0] += xv * wv.x;
                acc[i][1] += xv * wv.y;
                acc[i][2] += xv * wv.z;
                acc[i][3] += xv * wv.w;
            }
        }

        const int gh = th0 + ph;
        const int gw = tw0 + pw;
        #pragma unroll
        for (int i = 0; i < 16; i++) {
            int o = oc * 64 + og * 16 + i;
            float bb = Bout[o];
            float2 r0 = make_float2(acc[i][0] + bb, acc[i][1] + bb);
            float2 r1 = make_float2(acc[i][2] + bb, acc[i][3] + bb);
            size_t base = (((size_t)n * CIN + o) * 128 + 2 * gh) * 128 + 2 * gw;
            *(float2*)&Z[base]       = r0;
            *(float2*)&Z[base + 128] = r1;
        }
    }
}

// ---------------------------------------------------------------------------
extern "C" void kernel_launch(void* const* d_in, const int* in_sizes, int n_in,
                              void* d_out, int out_size, void* d_ws, size_t ws_size,
                              hipStream_t stream) {
    const float* x      = (const float*)d_in[0];
    const float* w_down = (const float*)d_in[1];
    const float* b_down = (const float*)d_in[2];
    const float* w_enc  = (const float*)d_in[3];
    const float* b_enc  = (const float*)d_in[4];
    const float* w_out  = (const float*)d_in[5];
    const float* b_out  = (const float*)d_in[6];
    float* z  = (float*)d_out;

    float* ws = (float*)d_ws;
    float* t1 = ws;                       // 4*128*4096 = 2,097,152 floats
    float* e  = t1 + (size_t)NB * CD * NPIX;   // 4*100*4096 = 1,638,400 floats
    float* xo = e  + (size_t)NB * CE * NPIX;   // 4*256*4096 = 4,194,304 floats

    // t1 = w_down @ x + b_down   (per-batch GEMM 128 x 256 x 4096)
    gemm1x1_kernel<<<dim3(64, 2, NB), 256, 0, stream>>>(w_down, x, b_down, t1, CD, CIN);
    // xo = w_out @ x             (per-batch GEMM 256 x 256 x 4096, no bias)
    gemm1x1_kernel<<<dim3(64, 4, NB), 256, 0, stream>>>(w_out, x, nullptr, xo, CIN, CIN);
    // e = conv3x3(t1) + b_enc
    conv3x3_kernel<<<dim3(16, 4, NB), 256, 0, stream>>>(t1, w_enc, b_enc, e);
    // z = softmax + reassembly + pixel-shuffle + bias
    carafe_kernel<<<dim3(64, NB), 256, 0, stream>>>(e, xo, b_out, z);
}

// Round 3
// 175.859 us; speedup vs baseline: 2.7567x; 2.7567x over previous
//
#include <hip/hip_runtime.h>
#include <hip/hip_bf16.h>

// CARAFE pipeline, MFMA-restructured.
// x: (4, 256, 64, 64) fp32
// w_down: (128, 256) ; b_down: (128)
// w_enc: (100, 128, 3, 3) ; b_enc: (100)
// w_out: (256, 256) ; b_out: (256)
// out z: (4, 256, 128, 128) fp32
//
// Dataflow:
//   prep:      cast w_down/w_out to bf16; reorder+cast w_enc -> Wr[112][1152] (k = tap*128+c, rows 100..111 zero)
//   transpose: x fp32 [n][c][pix] -> xT bf16 [n][pix][256]
//   gemm_down: t1T[pix][c] = xT @ w_down^T + b_down   (bf16 out, [n][4096][128])
//   gemm_out:  xoT[pix][c] = xT @ w_out^T             (bf16 out, [n][4096][256])
//   conv_mfma: e[n][100][4096] = conv3x3(t1) + b_enc  (implicit GEMM, fp32 out)
//   carafe:    softmax(25) + reassembly + pixel-shuffle + b_out -> z
//
// MFMA v_mfma_f32_16x16x32_bf16 layout (guide §3, m89-verified C/D):
//   A-frag: row = lane&15, k = (lane>>4)*8 + j  (8 contiguous bf16 = 16B)
//   B-frag: col = lane&15, k = (lane>>4)*8 + j
//   C/D:    col = lane&15, row = (lane>>4)*4 + r

#define NB    4
#define NPIX  4096

typedef short s16x8 __attribute__((ext_vector_type(8)));
typedef float f32x4 __attribute__((ext_vector_type(4)));

#define MFMA16(a, b, c) __builtin_amdgcn_mfma_f32_16x16x32_bf16((a), (b), (c), 0, 0, 0)

__device__ __forceinline__ ushort f2b(float f) {
    __hip_bfloat16 h = __float2bfloat16(f);
    return *(ushort*)&h;
}
__device__ __forceinline__ float b2f(ushort u) {
    unsigned v = ((unsigned)u) << 16;
    return *(float*)&v;
}

// ---------------------------------------------------------------------------
// prep: weight casts/reorders. 227,328 elements total, grid 888 x 256.
//   [0, 32768)          : w_down -> wdb bf16 (row-major [128][256])
//   [32768, 98304)      : w_out  -> wob bf16 (row-major [256][256])
//   [98304, 227328)     : w_enc  -> wrb bf16 [112][1152], k = tap*128 + c
// ---------------------------------------------------------------------------
__global__ __launch_bounds__(256) void prep_kernel(
    const float* __restrict__ wd, const float* __restrict__ wo,
    const float* __restrict__ we,
    ushort* __restrict__ wdb, ushort* __restrict__ wob, ushort* __restrict__ wrb)
{
    int idx = blockIdx.x * 256 + threadIdx.x;
    if (idx < 32768) {
        wdb[idx] = f2b(wd[idx]);
    } else if (idx < 98304) {
        int i = idx - 32768;
        wob[i] = f2b(wo[i]);
    } else if (idx < 227328) {
        int i = idx - 98304;
        int co = i / 1152, k = i - co * 1152;
        int tap = k >> 7, c = k & 127;
        float v = (co < 100) ? we[(co * 128 + c) * 9 + tap] : 0.0f;
        wrb[i] = f2b(v);
    }
}

// ---------------------------------------------------------------------------
// transpose-cast: x [n][256][4096] fp32 -> xT [n][4096][256] bf16.
// Block: 64-pixel tile. Thread t owns channel t; LDS transpose.
// ---------------------------------------------------------------------------
__global__ __launch_bounds__(256) void transpose_cast_kernel(
    const float* __restrict__ X, ushort* __restrict__ Xt)
{
    __shared__ ushort xs[64][264];   // pad 256->264 (row stride 528B, 16B mult)
    const int n = blockIdx.y, p0 = blockIdx.x * 64;
    const int tid = threadIdx.x;
    const float* Xn = X + (size_t)n * 256 * NPIX;

    #pragma unroll
    for (int j = 0; j < 16; j++) {
        float4 v = *(const float4*)&Xn[(size_t)tid * NPIX + p0 + j * 4];
        xs[j * 4 + 0][tid] = f2b(v.x);
        xs[j * 4 + 1][tid] = f2b(v.y);
        xs[j * 4 + 2][tid] = f2b(v.z);
        xs[j * 4 + 3][tid] = f2b(v.w);
    }
    __syncthreads();
    #pragma unroll
    for (int i = 0; i < 8; i++) {
        int flat = tid + 256 * i;          // 0..2047
        int pix = flat >> 5, c16 = flat & 31;
        s16x8 v = *(const s16x8*)&xs[pix][c16 * 8];
        *(s16x8*)&Xt[((size_t)(n * NPIX + p0 + pix)) * 256 + c16 * 8] = v;
    }
}

// ---------------------------------------------------------------------------
// gemm_mfma: Out[pix][c] = sum_k xT[pix][k] * W[c][k]  (+bias), bf16 out.
// Block: 64 pixels x COUT channels, 4 waves as 2(pix) x 2(chan).
// A = xT tile in LDS; B = W bf16 from global (L2-resident).
// ---------------------------------------------------------------------------
template<int COUT, bool BIAS>
__global__ __launch_bounds__(256, 1) void gemm_mfma_kernel(
    const ushort* __restrict__ Xt,   // [NB*4096][256]
    const ushort* __restrict__ Wb,   // [COUT][256]
    const float* __restrict__ bias,  // [COUT] or nullptr
    ushort* __restrict__ Out)        // [NB*4096][COUT]
{
    __shared__ ushort xs[64][264];
    const int n = blockIdx.y, p0 = blockIdx.x * 64;
    const int tid = threadIdx.x, lane = tid & 63, wid = tid >> 6;
    const int wp = wid >> 1, wc = wid & 1;
    const int l15 = lane & 15, l4 = lane >> 4;
    const ushort* Xn = Xt + (size_t)(n * NPIX + p0) * 256;

    #pragma unroll
    for (int i = 0; i < 8; i++) {
        int flat = tid + 256 * i;
        int row = flat >> 5, ch = flat & 31;
        s16x8 v = *(const s16x8*)&Xn[row * 256 + ch * 8];
        *(s16x8*)&xs[row][ch * 8] = v;
    }
    __syncthreads();

    constexpr int NCF = COUT / 32;       // c-frags per wave: 4 (128) or 8 (256)
    const int crow = wc * (COUT / 2);

    f32x4 acc[2][NCF] = {};

    #pragma unroll 2
    for (int ks = 0; ks < 8; ks++) {
        int k0 = ks * 32 + l4 * 8;
        s16x8 a0 = *(const s16x8*)&xs[wp * 32 + l15][k0];
        s16x8 a1 = *(const s16x8*)&xs[wp * 32 + 16 + l15][k0];
        #pragma unroll
        for (int cf = 0; cf < NCF; cf++) {
            s16x8 b = *(const s16x8*)&Wb[(size_t)(crow + cf * 16 + l15) * 256 + k0];
            acc[0][cf] = MFMA16(a0, b, acc[0][cf]);
            acc[1][cf] = MFMA16(a1, b, acc[1][cf]);
        }
    }

    #pragma unroll
    for (int pf = 0; pf < 2; pf++) {
        #pragma unroll
        for (int cf = 0; cf < NCF; cf++) {
            int c = crow + cf * 16 + l15;
            float bb = BIAS ? bias[c] : 0.0f;
            #pragma unroll
            for (int r = 0; r < 4; r++) {
                int pix = p0 + wp * 32 + pf * 16 + l4 * 4 + r;
                Out[(size_t)(n * NPIX + pix) * COUT + c] = f2b(acc[pf][cf][r] + bb);
            }
        }
    }
}

// ---------------------------------------------------------------------------
// conv_mfma: e[n][co][pix] = sum_{tap,c} Wr[co][tap*128+c] * t1T[shift(pix,tap)][c] + b_enc
// Block: 8x8 pixel tile, all 112 (7x16) co. 4 waves each own 16 pixels.
// B from LDS halo (10x10 x 128ch bf16); A from global Wr (L2).
// One __syncthreads total.
// ---------------------------------------------------------------------------
__global__ __launch_bounds__(256, 1) void conv_mfma_kernel(
    const ushort* __restrict__ T1t,  // [NB*4096][128]
    const ushort* __restrict__ Wr,   // [112][1152]
    const float* __restrict__ Benc,  // [100]
    float* __restrict__ E)           // [NB][100][4096]
{
    __shared__ ushort hs[100][136];  // 10x10 halo pixels x 128 ch (pad->136)
    const int n = blockIdx.y, tile = blockIdx.x;
    const int h0 = (tile >> 3) * 8, w0 = (tile & 7) * 8;
    const int tid = threadIdx.x, lane = tid & 63, wid = tid >> 6;
    const int l15 = lane & 15, l4 = lane >> 4;

    // stage halo: 100 pixels x 256B (16 x 16B units each)
    for (int u = tid; u < 1600; u += 256) {
        int hp = u >> 4, ch = u & 15;
        int r = hp / 10, s = hp - r * 10;
        int gh = h0 - 1 + r, gw = w0 - 1 + s;
        s16x8 v = {};
        if ((unsigned)gh < 64u && (unsigned)gw < 64u)
            v = *(const s16x8*)&T1t[((size_t)n * NPIX + gh * 64 + gw) * 128 + ch * 8];
        *(s16x8*)&hs[hp][ch * 8] = v;
    }
    __syncthreads();

    const int pl = wid * 16 + l15;        // this lane's pixel (B col / D col)
    const int ph = pl >> 3, pw = pl & 7;

    f32x4 acc[7] = {};

    for (int tap = 0; tap < 9; tap++) {
        int dy = tap / 3, dx = tap - dy * 3;
        int hp = (ph + dy) * 10 + (pw + dx);
        const ushort* hrow = &hs[hp][l4 * 8];
        const ushort* wrow = &Wr[(size_t)l15 * 1152 + tap * 128 + l4 * 8];
        #pragma unroll
        for (int cb = 0; cb < 4; cb++) {
            s16x8 b = *(const s16x8*)&hrow[cb * 32];
            #pragma unroll
            for (int mf = 0; mf < 7; mf++) {
                s16x8 a = *(const s16x8*)&wrow[(size_t)mf * 16 * 1152 + cb * 32];
                acc[mf] = MFMA16(a, b, acc[mf]);
            }
        }
    }

    const int gpix = (h0 + ph) * 64 + w0 + pw;
    #pragma unroll
    for (int mf = 0; mf < 7; mf++) {
        #pragma unroll
        for (int r = 0; r < 4; r++) {
            int co = mf * 16 + l4 * 4 + r;
            if (co < 100)
                E[((size_t)n * 100 + co) * NPIX + gpix] = acc[mf][r] + Benc[co];
        }
    }
}

// ---------------------------------------------------------------------------
// carafe: softmax(25 taps, per sub-pixel) + reassembly + bias + pixel-shuffle.
// Grid: (64 tiles, 4 oc-chunks, 4 batches) = 1024 blocks.
// z[n,o,2h+a,2w+b] = b_out[o] + sum_k sm[k][h,w][p] * xo[o][h+di-2][w+dj-2]
// ---------------------------------------------------------------------------
__global__ __launch_bounds__(256) void carafe_kernel(
    const float* __restrict__ E,     // [NB][100][4096]
    const ushort* __restrict__ XOt,  // [NB*4096][256] bf16
    const float* __restrict__ Bout,  // [256]
    float* __restrict__ Z)           // [NB][256][128][128]
{
    __shared__ __attribute__((aligned(16))) float sm[25][64][4];  // 25.6 KB
    __shared__ float xs[64][145];                                 // 37.1 KB

    const int n = blockIdx.z, oc = blockIdx.y, tile = blockIdx.x;
    const int th0 = (tile >> 3) * 8, tw0 = (tile & 7) * 8;
    const int tid = threadIdx.x;

    // ---- softmax over 25 taps for each (pixel, sub-pixel p) ----
    {
        int p = tid & 3, pix = tid >> 2;
        int gh = th0 + (pix >> 3), gw = tw0 + (pix & 7);
        const float* En = E + (size_t)n * 100 * NPIX + gh * 64 + gw;
        float v[25];
        float mx = -1e30f;
        #pragma unroll
        for (int k = 0; k < 25; k++) {
            v[k] = En[(size_t)(k * 4 + p) * NPIX];
            mx = fmaxf(mx, v[k]);
        }
        float s = 0.0f;
        #pragma unroll
        for (int k = 0; k < 25; k++) { v[k] = __expf(v[k] - mx); s += v[k]; }
        float inv = 1.0f / s;
        #pragma unroll
        for (int k = 0; k < 25; k++) sm[k][pix][p] = v[k] * inv;
    }

    // ---- stage 12x12 halo x 64 ch of xo (bf16 -> fp32, transposed) ----
    for (int u = tid; u < 2304; u += 256) {   // 144 px x 16 groups of 4 ch
        int hp = u >> 4, cg = u & 15;
        int r = hp / 12, s = hp - r * 12;
        int gh = th0 - 2 + r, gw = tw0 - 2 + s;
        float v0 = 0.f, v1 = 0.f, v2 = 0.f, v3 = 0.f;
        if ((unsigned)gh < 64u && (unsigned)gw < 64u) {
            const ushort* src = &XOt[((size_t)n * NPIX + gh * 64 + gw) * 256 + oc * 64 + cg * 4];
            ushort4 raw = *(const ushort4*)src;
            v0 = b2f(raw.x); v1 = b2f(raw.y); v2 = b2f(raw.z); v3 = b2f(raw.w);
        }
        xs[cg * 4 + 0][hp] = v0;
        xs[cg * 4 + 1][hp] = v1;
        xs[cg * 4 + 2][hp] = v2;
        xs[cg * 4 + 3][hp] = v3;
    }
    __syncthreads();

    // ---- reassembly: each thread = (pixel, 16-ch group) ----
    const int pix = tid & 63;
    const int og = tid >> 6;
    const int ph = pix >> 3, pw = pix & 7;

    float acc[16][4] = {};
    for (int k = 0; k < 25; k++) {
        int di = k / 5, dj = k - di * 5;
        float4 wv = *(const float4*)&sm[k][pix][0];
        int base = (ph + di) * 12 + pw + dj;
        #pragma unroll
        for (int i = 0; i < 16; i++) {
            float xv = xs[og * 16 + i][base];
            acc[i][0] += xv * wv.x;
            acc[i][1] += xv * wv.y;
            acc[i][2] += xv * wv.z;
            acc[i][3] += xv * wv.w;
        }
    }

    const int gh = th0 + ph, gw = tw0 + pw;
    #pragma unroll
    for (int i = 0; i < 16; i++) {
        int o = oc * 64 + og * 16 + i;
        float bb = Bout[o];
        float2 r0 = make_float2(acc[i][0] + bb, acc[i][1] + bb);
        float2 r1 = make_float2(acc[i][2] + bb, acc[i][3] + bb);
        size_t base = (((size_t)n * 256 + o) * 128 + 2 * gh) * 128 + 2 * gw;
        *(float2*)&Z[base]       = r0;
        *(float2*)&Z[base + 128] = r1;
    }
}

// ---------------------------------------------------------------------------
extern "C" void kernel_launch(void* const* d_in, const int* in_sizes, int n_in,
                              void* d_out, int out_size, void* d_ws, size_t ws_size,
                              hipStream_t stream) {
    const float* x      = (const float*)d_in[0];
    const float* w_down = (const float*)d_in[1];
    const float* b_down = (const float*)d_in[2];
    const float* w_enc  = (const float*)d_in[3];
    const float* b_enc  = (const float*)d_in[4];
    const float* w_out  = (const float*)d_in[5];
    const float* b_out  = (const float*)d_in[6];
    float* z = (float*)d_out;

    // workspace layout
    ushort* xT  = (ushort*)d_ws;            // 4*4096*256
    ushort* t1T = xT + 4194304;             // 4*4096*128
    ushort* xoT = t1T + 2097152;            // 4*4096*256
    float*  e   = (float*)(xoT + 4194304);  // 4*100*4096
    ushort* wdb = (ushort*)(e + 1638400);   // 128*256
    ushort* wob = wdb + 32768;              // 256*256
    ushort* wrb = wob + 65536;              // 112*1152

    prep_kernel<<<888, 256, 0, stream>>>(w_down, w_out, w_enc, wdb, wob, wrb);
    transpose_cast_kernel<<<dim3(64, NB), 256, 0, stream>>>(x, xT);
    gemm_mfma_kernel<128, true><<<dim3(64, NB), 256, 0, stream>>>(xT, wdb, b_down, t1T);
    gemm_mfma_kernel<256, false><<<dim3(64, NB), 256, 0, stream>>>(xT, wob, nullptr, xoT);
    conv_mfma_kernel<<<dim3(64, NB), 256, 0, stream>>>(t1T, wrb, b_enc, e);
    carafe_kernel<<<dim3(64, 4, NB), 256, 0, stream>>>(e, xoT, b_out, z);
}

// Round 4
// 170.113 us; speedup vs baseline: 2.8498x; 1.0338x over previous
//
#include <hip/hip_runtime.h>
#include <hip/hip_bf16.h>

// CARAFE pipeline, fully fused (3 kernels).
// x: (4, 256, 64, 64) fp32
// w_down: (128, 256) ; b_down: (128)
// w_enc: (100, 128, 3, 3) ; b_enc: (100)
// w_out: (256, 256) ; b_out: (256)
// out z: (4, 256, 128, 128) fp32
//
// Pipeline:
//   prep:        wcomb bf16 [384][256] = [w_down ; w_out] ; wrb bf16 [112][1152] (k = tap*128+c)
//   dual_gemm:   x --(LDS transpose-cast)--> t1T bf16 [n*4096][128] (+b_down), xoT bf16 [n*4096][256]
//   carafe_fused: conv3x3(MFMA) -> e_lds -> softmax(25) -> sm_lds -> reassembly + b_out + pixel-shuffle -> z
//
// MFMA v_mfma_f32_16x16x32_bf16 layout (guide §3, m89-verified):
//   A-frag: row = lane&15, k = (lane>>4)*8 + j
//   B-frag: col = lane&15, k = (lane>>4)*8 + j
//   C/D:    col = lane&15, row = (lane>>4)*4 + r
// Conv C-frag -> softmax mapping: co = 16*mf + 4*l4 + r, co = 4k+p  =>  k = 4*mf+l4, p = r.

#define NB    4
#define NPIX  4096

typedef short s16x8 __attribute__((ext_vector_type(8)));
typedef float f32x4 __attribute__((ext_vector_type(4)));

#define MFMA16(a, b, c) __builtin_amdgcn_mfma_f32_16x16x32_bf16((a), (b), (c), 0, 0, 0)

__device__ __forceinline__ ushort f2b(float f) {
    __hip_bfloat16 h = __float2bfloat16(f);
    return *(ushort*)&h;
}
__device__ __forceinline__ float b2f(ushort u) {
    unsigned v = ((unsigned)u) << 16;
    return *(float*)&v;
}

// ---------------------------------------------------------------------------
// prep: weight casts/reorders. 227,328 elements, grid 888 x 256.
//   [0, 98304)       : wcomb = [w_down (rows 0..127) ; w_out (rows 128..383)]
//   [98304, 227328)  : w_enc -> wrb [112][1152], k = tap*128 + c, rows 100..111 zero
// ---------------------------------------------------------------------------
__global__ __launch_bounds__(256) void prep_kernel(
    const float* __restrict__ wd, const float* __restrict__ wo,
    const float* __restrict__ we,
    ushort* __restrict__ wcomb, ushort* __restrict__ wrb)
{
    int idx = blockIdx.x * 256 + threadIdx.x;
    if (idx < 98304) {
        float v = (idx < 32768) ? wd[idx] : wo[idx - 32768];
        wcomb[idx] = f2b(v);
    } else if (idx < 227328) {
        int i = idx - 98304;
        int co = i / 1152, k = i - co * 1152;
        int tap = k >> 7, c = k & 127;
        float v = (co < 100) ? we[(co * 128 + c) * 9 + tap] : 0.0f;
        wrb[i] = f2b(v);
    }
}

// ---------------------------------------------------------------------------
// dual_gemm: Out[pix][0..127] = t1T (+b_down) ; Out[pix][128..383] = xoT.
// Block: 64 pixels, 512 threads (8 waves as 4 pixel-groups x 2 channel-halves).
// x is read directly (fp32) and transpose-cast into LDS.
// ---------------------------------------------------------------------------
__global__ __launch_bounds__(512, 1) void dual_gemm_kernel(
    const float*  __restrict__ X,      // [NB][256][4096]
    const ushort* __restrict__ Wcomb,  // [384][256]
    const float*  __restrict__ b_down, // [128]
    ushort* __restrict__ T1t,          // [NB*4096][128]
    ushort* __restrict__ XOt)          // [NB*4096][256]
{
    __shared__ __attribute__((aligned(16))) ushort xs[64][264];
    const int n = blockIdx.y, p0 = blockIdx.x * 64;
    const int tid = threadIdx.x, lane = tid & 63, wid = tid >> 6;
    const int l15 = lane & 15, l4 = lane >> 4;
    const float* Xn = X + (size_t)n * 256 * NPIX + p0;

    // stage + transpose-cast: thread (c = tid>>1) covers 32 pixels (half = tid&1)
    {
        int c = tid >> 1, half = tid & 1;
        const float* src = Xn + (size_t)c * NPIX + half * 32;
        #pragma unroll
        for (int j = 0; j < 8; j++) {
            float4 v = *(const float4*)&src[j * 4];
            int pix = half * 32 + j * 4;
            xs[pix + 0][c] = f2b(v.x);
            xs[pix + 1][c] = f2b(v.y);
            xs[pix + 2][c] = f2b(v.z);
            xs[pix + 3][c] = f2b(v.w);
        }
    }
    __syncthreads();

    const int wp = wid >> 1;        // 0..3: 16-pixel group
    const int wc = wid & 1;         // 0..1: 192-channel half
    const int crow = wc * 192;

    f32x4 acc[12] = {};
    #pragma unroll
    for (int ks = 0; ks < 8; ks++) {
        int k0 = ks * 32 + l4 * 8;
        s16x8 a = *(const s16x8*)&xs[wp * 16 + l15][k0];
        #pragma unroll
        for (int cf = 0; cf < 12; cf++) {
            s16x8 b = *(const s16x8*)&Wcomb[(size_t)(crow + cf * 16 + l15) * 256 + k0];
            acc[cf] = MFMA16(a, b, acc[cf]);
        }
    }

    #pragma unroll
    for (int cf = 0; cf < 12; cf++) {
        int cbase = crow + cf * 16;       // wave-uniform
        int c = cbase + l15;
        if (cbase < 128) {
            float bb = b_down[c];
            #pragma unroll
            for (int r = 0; r < 4; r++) {
                int pix = p0 + wp * 16 + l4 * 4 + r;
                T1t[(size_t)(n * NPIX + pix) * 128 + c] = f2b(acc[cf][r] + bb);
            }
        } else {
            int c2 = c - 128;
            #pragma unroll
            for (int r = 0; r < 4; r++) {
                int pix = p0 + wp * 16 + l4 * 4 + r;
                XOt[(size_t)(n * NPIX + pix) * 256 + c2] = f2b(acc[cf][r]);
            }
        }
    }
}

// ---------------------------------------------------------------------------
// carafe_fused: conv3x3(t1) + b_enc -> softmax(25) -> reassembly + b_out -> z.
// Block: one 8x8 tile of one batch, 512 threads (8 waves). Grid (64, NB).
// LDS: region A = t1-halo hs[100][136] (27.2KB), later sm[25][64][4] (25.6KB)
//      region B = e_lds[64][101] (25.9KB), later xs[128][145] (74.2KB)
// ---------------------------------------------------------------------------
#define SMEM_A 27264
#define SMEM_TOTAL (SMEM_A + 74240)

__global__ __launch_bounds__(512, 1) void carafe_fused_kernel(
    const ushort* __restrict__ T1t,  // [NB*4096][128]
    const ushort* __restrict__ Wr,   // [112][1152]
    const float*  __restrict__ Benc, // [100]
    const ushort* __restrict__ XOt,  // [NB*4096][256]
    const float*  __restrict__ Bout, // [256]
    float* __restrict__ Z)           // [NB][256][128][128]
{
    __shared__ __attribute__((aligned(16))) char smem[SMEM_TOTAL];
    ushort (*hs)[136]   = (ushort(*)[136])smem;            // phase 1-2
    float  (*sm)[64][4] = (float(*)[64][4])smem;           // phase 3+  (aliases hs)
    float  (*eld)[101]  = (float(*)[101])(smem + SMEM_A);  // phase 2-3
    float  (*xs)[145]   = (float(*)[145])(smem + SMEM_A);  // phase 4   (aliases eld)

    const int n = blockIdx.y, tile = blockIdx.x;
    const int h0 = (tile >> 3) * 8, w0 = (tile & 7) * 8;
    const int tid = threadIdx.x, lane = tid & 63, wid = tid >> 6;
    const int l15 = lane & 15, l4 = lane >> 4;

    // ---- phase 1: stage t1 halo (10x10 pixels x 128 ch bf16) ----
    for (int u = tid; u < 1600; u += 512) {
        int hp = u >> 4, ch = u & 15;
        int r = hp / 10, s = hp - r * 10;
        int gh = h0 - 1 + r, gw = w0 - 1 + s;
        s16x8 v = {};
        if ((unsigned)gh < 64u && (unsigned)gw < 64u)
            v = *(const s16x8*)&T1t[((size_t)n * NPIX + gh * 64 + gw) * 128 + ch * 8];
        *(s16x8*)&hs[hp][ch * 8] = v;
    }
    __syncthreads();

    // ---- phase 2: conv via MFMA (waves 0-3), e -> LDS ----
    if (wid < 4) {
        const int pl = wid * 16 + l15;      // pixel in tile (B col / D col)
        const int ph = pl >> 3, pw = pl & 7;
        f32x4 acc[7] = {};
        for (int tap = 0; tap < 9; tap++) {
            int dy = tap / 3, dx = tap - dy * 3;
            int hp = (ph + dy) * 10 + pw + dx;
            const ushort* hrow = &hs[hp][l4 * 8];
            const ushort* wrow = &Wr[(size_t)l15 * 1152 + tap * 128 + l4 * 8];
            #pragma unroll
            for (int cb = 0; cb < 4; cb++) {
                s16x8 b = *(const s16x8*)&hrow[cb * 32];
                #pragma unroll
                for (int mf = 0; mf < 7; mf++) {
                    s16x8 a = *(const s16x8*)&wrow[(size_t)mf * 16 * 1152 + cb * 32];
                    acc[mf] = MFMA16(a, b, acc[mf]);
                }
            }
        }
        #pragma unroll
        for (int mf = 0; mf < 7; mf++) {
            #pragma unroll
            for (int r = 0; r < 4; r++) {
                int co = mf * 16 + l4 * 4 + r;
                if (co < 100) eld[pl][co] = acc[mf][r] + Benc[co];
            }
        }
    }
    __syncthreads();

    // ---- phase 3: softmax over 25 taps per (pixel, sub-pixel) ----
    if (tid < 256) {
        int p = tid & 3, pix = tid >> 2;
        float v[25];
        float mx = -1e30f;
        #pragma unroll
        for (int k = 0; k < 25; k++) { v[k] = eld[pix][4 * k + p]; mx = fmaxf(mx, v[k]); }
        float ssum = 0.0f;
        #pragma unroll
        for (int k = 0; k < 25; k++) { v[k] = __expf(v[k] - mx); ssum += v[k]; }
        float inv = 1.0f / ssum;
        #pragma unroll
        for (int k = 0; k < 25; k++) sm[k][pix][p] = v[k] * inv;
    }
    __syncthreads();

    // ---- phase 4: reassembly, 2 oc-chunks (128 ch) staged per iteration ----
    const int pix = tid & 63;
    const int og8 = tid >> 6;          // 0..7
    const int ph = pix >> 3, pw = pix & 7;
    const int cl = og8 >> 2;           // chunk-local 0/1
    const int g  = og8 & 3;            // 16-ch group within chunk

    for (int it = 0; it < 2; it++) {
        // stage 12x12 halo x 128 ch of xo (bf16 -> fp32, transposed)
        for (int u = tid; u < 4608; u += 512) {   // 144 px x 32 groups of 4 ch
            int hp = u >> 5, cg = u & 31;
            int r = hp / 12, s = hp - r * 12;
            int gh = h0 - 2 + r, gw = w0 - 2 + s;
            float v0 = 0.f, v1 = 0.f, v2 = 0.f, v3 = 0.f;
            if ((unsigned)gh < 64u && (unsigned)gw < 64u) {
                ushort4 raw = *(const ushort4*)&XOt[((size_t)n * NPIX + gh * 64 + gw) * 256 + it * 128 + cg * 4];
                v0 = b2f(raw.x); v1 = b2f(raw.y); v2 = b2f(raw.z); v3 = b2f(raw.w);
            }
            xs[cg * 4 + 0][hp] = v0;
            xs[cg * 4 + 1][hp] = v1;
            xs[cg * 4 + 2][hp] = v2;
            xs[cg * 4 + 3][hp] = v3;
        }
        __syncthreads();

        float acc[16][4] = {};
        for (int k = 0; k < 25; k++) {
            int di = k / 5, dj = k - di * 5;
            float4 wv = *(const float4*)&sm[k][pix][0];
            int base = (ph + di) * 12 + pw + dj;
            #pragma unroll
            for (int i = 0; i < 16; i++) {
                float xv = xs[cl * 64 + g * 16 + i][base];
                acc[i][0] += xv * wv.x;
                acc[i][1] += xv * wv.y;
                acc[i][2] += xv * wv.z;
                acc[i][3] += xv * wv.w;
            }
        }

        const int gh = h0 + ph, gw = w0 + pw;
        const int oc = it * 2 + cl;
        #pragma unroll
        for (int i = 0; i < 16; i++) {
            int o = oc * 64 + g * 16 + i;
            float bb = Bout[o];
            float2 r0 = make_float2(acc[i][0] + bb, acc[i][1] + bb);
            float2 r1 = make_float2(acc[i][2] + bb, acc[i][3] + bb);
            size_t zb = (((size_t)n * 256 + o) * 128 + 2 * gh) * 128 + 2 * gw;
            *(float2*)&Z[zb]       = r0;
            *(float2*)&Z[zb + 128] = r1;
        }
        if (it == 0) __syncthreads();   // xs re-staged next iteration
    }
}

// ---------------------------------------------------------------------------
extern "C" void kernel_launch(void* const* d_in, const int* in_sizes, int n_in,
                              void* d_out, int out_size, void* d_ws, size_t ws_size,
                              hipStream_t stream) {
    const float* x      = (const float*)d_in[0];
    const float* w_down = (const float*)d_in[1];
    const float* b_down = (const float*)d_in[2];
    const float* w_enc  = (const float*)d_in[3];
    const float* b_enc  = (const float*)d_in[4];
    const float* w_out  = (const float*)d_in[5];
    const float* b_out  = (const float*)d_in[6];
    float* z = (float*)d_out;

    // workspace layout (ushort elements)
    ushort* t1T   = (ushort*)d_ws;        // 4*4096*128 = 2,097,152
    ushort* xoT   = t1T + 2097152;        // 4*4096*256 = 4,194,304
    ushort* wcomb = xoT + 4194304;        // 384*256    =    98,304
    ushort* wrb   = wcomb + 98304;        // 112*1152   =   129,024

    prep_kernel<<<888, 256, 0, stream>>>(w_down, w_out, w_enc, wcomb, wrb);
    dual_gemm_kernel<<<dim3(64, NB), 512, 0, stream>>>(x, wcomb, b_down, t1T, xoT);
    carafe_fused_kernel<<<dim3(64, NB), 512, 0, stream>>>(t1T, wrb, b_enc, xoT, b_out, z);
}